// Round 12
// baseline (441.968 us; speedup 1.0000x reference)
//
#include <hip/hip_runtime.h>
#include <stdint.h>

#define NN   8192
#define DIN  512
#define DOUT 512
#define ALPHA 0.2f

typedef float          floatx4  __attribute__((ext_vector_type(4)));
typedef float          floatx2  __attribute__((ext_vector_type(2)));
typedef short          shortx8  __attribute__((ext_vector_type(8)));
typedef unsigned short ushortx4 __attribute__((ext_vector_type(4)));
typedef int            intx2    __attribute__((ext_vector_type(2)));
typedef int            intx4    __attribute__((ext_vector_type(4)));
typedef unsigned       uintx2   __attribute__((ext_vector_type(2)));

__device__ inline unsigned short f2bf(float x) {
    union { float f; unsigned u; } v; v.f = x;
    return (unsigned short)((v.u + 0x7FFFu + ((v.u >> 16) & 1u)) >> 16);
}
__device__ inline unsigned encf(float x) {
    union { float f; unsigned u; } v; v.f = x;
    return (v.u & 0x80000000u) ? ~v.u : (v.u | 0x80000000u);
}
__device__ inline float decf(unsigned e) {
    union { float f; unsigned u; } v;
    v.u = (e & 0x80000000u) ? (e & 0x7FFFFFFFu) : ~e;
    return v.f;
}
__device__ inline float lrelu(float x) { return fmaxf(x, ALPHA * x); }

// ---------------------------------------------------------------------------
// Kernel T: WT[n][k] = bf16(W[k][n])   (512x512)
// ---------------------------------------------------------------------------
__global__ __launch_bounds__(256) void transpose_w(const float* __restrict__ W,
                                                   unsigned short* __restrict__ WT) {
    __shared__ float tile[32][33];
    const int t = threadIdx.x;
    const int x = t & 31, y = t >> 5;
    const int tr = (blockIdx.x >> 4) * 32, tc = (blockIdx.x & 15) * 32;
#pragma unroll
    for (int i = 0; i < 4; i++) {
        int r = y + i * 8;
        tile[r][x] = W[(size_t)(tr + r) * DOUT + tc + x];
    }
    __syncthreads();
#pragma unroll
    for (int i = 0; i < 4; i++) {
        int r = y + i * 8;
        WT[(size_t)(tc + r) * DIN + tr + x] = f2bf(tile[x][r]);
    }
}

// ---------------------------------------------------------------------------
// Kernel A: Wh = h @ W (bf16 MFMA). R16: 256 blocks x 512 threads, 32 rows
// per block as TWO independent 16-row halves (half = w>>2, wsub = w&3).
// Each half replicates the old 4-wave block exactly (same fragments, same
// reduction order -> bitwise-identical output); WT L2 re-read traffic halves
// (268 -> 134 MB, the old kernel's co-limiter at ~20 TB/s). Occupancy
// unchanged (8 waves/CU). Writes WhTt k-major fragment-tiled, f1, f2, max(f2).
// ---------------------------------------------------------------------------
__global__ __launch_bounds__(512) void gemm_wh(
    const float* __restrict__ h, const unsigned short* __restrict__ WT,
    const float* __restrict__ a, unsigned short* __restrict__ WhTt,
    float* __restrict__ f1, float* __restrict__ f2, unsigned* __restrict__ Menc)
{
    __shared__ float f1s[2][4][16], f2s[2][4][16];
    const int t = threadIdx.x;
    const int w = t >> 6, lane = t & 63, l15 = lane & 15, q = lane >> 4;
    const int half = w >> 2, wsub = w & 3;
    const int r0 = blockIdx.x * 32 + half * 16;
    const int wc0 = wsub * 128;

    floatx4 acc[8];
    const floatx4 z4 = {0.f, 0.f, 0.f, 0.f};
#pragma unroll
    for (int j = 0; j < 8; j++) acc[j] = z4;

    const float* hp = &h[(size_t)(r0 + l15) * DIN + q * 8];
    const unsigned short* bp = &WT[(size_t)(wc0 + l15) * DIN + q * 8];

    floatx4 hA[2][2];
    shortx8 bB[2][8];
    hA[0][0] = *(const floatx4*)hp;
    hA[0][1] = *(const floatx4*)(hp + 4);
#pragma unroll
    for (int nt = 0; nt < 8; nt++)
        bB[0][nt] = *(const shortx8*)(bp + (size_t)nt * 16 * DIN);

#pragma unroll 2
    for (int it = 0; it < 16; ++it) {
        const int c = it & 1, n = c ^ 1;
        const int kn = ((it + 1) & 15) * 32;
        hA[n][0] = *(const floatx4*)(hp + kn);
        hA[n][1] = *(const floatx4*)(hp + kn + 4);
#pragma unroll
        for (int nt = 0; nt < 8; nt++)
            bB[n][nt] = *(const shortx8*)(bp + (size_t)nt * 16 * DIN + kn);

        shortx8 af;
#pragma unroll
        for (int j = 0; j < 8; j++)
            af[j] = (short)f2bf(hA[c][j >> 2][j & 3]);
#pragma unroll
        for (int nt = 0; nt < 8; nt++)
            acc[nt] = __builtin_amdgcn_mfma_f32_16x16x32_bf16(af, bB[c][nt], acc[nt], 0, 0, 0);
    }

    float a1v[8], a2v[8];
#pragma unroll
    for (int nt = 0; nt < 8; nt++) {
        int col = wc0 + nt * 16 + l15;
        a1v[nt] = a[col];
        a2v[nt] = a[DOUT + col];
    }
    {
        const int kk0 = r0 + q * 4;
        const int tile_k = kk0 >> 5;
        const int qq = (kk0 >> 3) & 3;
        const int j0 = kk0 & 7;
#pragma unroll
        for (int nt = 0; nt < 8; nt++) {
            const int tile_n = wsub * 8 + nt;
            ushortx4 pk;
#pragma unroll
            for (int reg = 0; reg < 4; reg++) pk[reg] = f2bf(acc[nt][reg]);
            *(ushortx4*)&WhTt[(((size_t)tile_k * 32 + tile_n) << 9) + qq * 128 + l15 * 8 + j0] = pk;
        }
    }
    float s1a[4], s2a[4];
#pragma unroll
    for (int reg = 0; reg < 4; reg++) {
        float s1 = 0.f, s2 = 0.f;
#pragma unroll
        for (int nt = 0; nt < 8; nt++) {
            s1 += acc[nt][reg] * a1v[nt];
            s2 += acc[nt][reg] * a2v[nt];
        }
        s1 += __shfl_xor(s1, 1, 64); s2 += __shfl_xor(s2, 1, 64);
        s1 += __shfl_xor(s1, 2, 64); s2 += __shfl_xor(s2, 2, 64);
        s1 += __shfl_xor(s1, 4, 64); s2 += __shfl_xor(s2, 4, 64);
        s1 += __shfl_xor(s1, 8, 64); s2 += __shfl_xor(s2, 8, 64);
        s1a[reg] = s1; s2a[reg] = s2;
    }
    if (l15 == 0) {
#pragma unroll
        for (int reg = 0; reg < 4; reg++) {
            f1s[half][wsub][q * 4 + reg] = s1a[reg];
            f2s[half][wsub][q * 4 + reg] = s2a[reg];
        }
    }
    __syncthreads();
    if (t < 32) {
        const int hh = t >> 4, idx = t & 15;
        float v1 = f1s[hh][0][idx] + f1s[hh][1][idx] + f1s[hh][2][idx] + f1s[hh][3][idx];
        float v2 = f2s[hh][0][idx] + f2s[hh][1][idx] + f2s[hh][2][idx] + f2s[hh][3][idx];
        const int row = blockIdx.x * 32 + hh * 16 + idx;
        f1[row] = v1;
        f2[row] = v2;
        float mx = v2;      // xor 1,2,4,8 stays within each aligned 16-lane group
        mx = fmaxf(mx, __shfl_xor(mx, 1, 64));
        mx = fmaxf(mx, __shfl_xor(mx, 2, 64));
        mx = fmaxf(mx, __shfl_xor(mx, 4, 64));
        mx = fmaxf(mx, __shfl_xor(mx, 8, 64));
        if (idx == 0) atomicMax(Menc, encf(mx));
    }
}

// ---------------------------------------------------------------------------
// Kernel 2: GAT aggregation, R16 = R11 VERBATIM (434.4 champion: clustered
// pre-barrier produce, f2s in LDS, acc[8][2], grouped barrier GRP=4, stagger,
// setprio, row-major plain P stores) + ONE change: pbuf row stride 40 -> 44
// shorts (80 -> 88 B). Stride-80 = bank-stride 20 (mod 32): only 8 distinct
// bank-starts for 16 l15 values / 8 prow-groups -> 4-8-way aliasing on the
// b64 p-writes; R14 profile measured SQ_LDS_BANK_CONFLICT 9.5M/dispatch
// (~580 cyc/iter = 19%). Stride-88 = bank-stride 22 (gcd 2): all 16 l15
// starts distinct, all 8 write-group starts distinct -> uniform <=2-way
// (free, m136). Pure index change: bitwise-identical; LDS 92 -> 100 KB
// (still 1 block/CU). R15's tiled-P epilogue reverted (measured +5 vs R11).
// ---------------------------------------------------------------------------
__global__ __launch_bounds__(1024, 4) void gat_agg(
    const int* __restrict__ adj, const unsigned short* __restrict__ WhTt,
    const float* __restrict__ f1, const float* __restrict__ f2,
    const unsigned* __restrict__ Menc, float* __restrict__ P,
    float* __restrict__ D)
{
    __shared__ __align__(16) unsigned short pbuf[2][4][128 * 44]; // 88 KB
    __shared__ float f2s[2048];                                   // 8 KB
    __shared__ float lsp[8][128];                                 // 4 KB

    const int t = threadIdx.x;
    const int w = t >> 6, lane = t & 63, l15 = lane & 15, q = lane >> 4;
    const int prow = t >> 3, pk = t & 7;      // p ownership: row, 4-k chunk

    const int kq = blockIdx.x & 3;            // XCD-constant k-quarter
    const int rgid = blockIdx.x >> 2;
    const int r0 = rgid * 128;
    const int k0 = kq * 2048;
    const int it0 = ((blockIdx.x >> 3) * 4) & 63;  // group-aligned k-stagger

    // stage f2 slice for this k-quarter into LDS
    *(floatx2*)&f2s[t * 2] = *(const floatx2*)&f2[k0 + t * 2];

    const float M = decf(*Menc);
    const float f1v = f1[r0 + prow];
    const float mi = lrelu(f1v + M);

    floatx4 acc[8][2];
    const floatx4 z4 = {0.f, 0.f, 0.f, 0.f};
#pragma unroll
    for (int i = 0; i < 8; i++)
#pragma unroll
        for (int j = 0; j < 2; j++) acc[i][j] = z4;
    float ls = 0.f;

    // B base: tile_k = kq*64 + phys, tile_n = w*2 + nt (unique per wave)
    const unsigned short* bpp = WhTt
        + (((size_t)(kq * 64) * 32 + w * 2) << 9) + lane * 8;
    const int* arp = adj + (size_t)(r0 + prow) * NN + k0 + pk * 4;

    intx4   adjr[4];
    shortx8 breg[2][2];

    __syncthreads();   // f2s visible

    // prologue: adj for group 0 (phys tiles it0..it0+3); B for flat tile 0
#pragma unroll
    for (int j = 0; j < 4; j++)
        adjr[j] = __builtin_nontemporal_load((const intx4*)(arp + ((it0 + j) & 63) * 32));
    breg[0][0] = *(const shortx8*)(bpp + (size_t)it0 * 16384);
    breg[0][1] = *(const shortx8*)(bpp + (size_t)it0 * 16384 + 512);

#pragma unroll 1
    for (int g = 0; g < 16; ++g) {
        const int gb = g & 1;

        // PRODUCE: p for 4 tiles of group g -> pbuf[gb][0..3]
#pragma unroll
        for (int j = 0; j < 4; j++) {
            const int px = (g * 4 + j + it0) & 63;
            const floatx4 ff = *(const floatx4*)&f2s[px * 32 + pk * 4];
            const intx4   ad = adjr[j];
            float p0 = __expf(lrelu(f1v + ff[0]) - mi);
            float p1 = __expf(lrelu(f1v + ff[1]) - mi);
            float p2 = __expf(lrelu(f1v + ff[2]) - mi);
            float p3 = __expf(lrelu(f1v + ff[3]) - mi);
            p0 = (ad[0] > 0) ? p0 : 0.f;
            p1 = (ad[1] > 0) ? p1 : 0.f;
            p2 = (ad[2] > 0) ? p2 : 0.f;
            p3 = (ad[3] > 0) ? p3 : 0.f;
            ls += (p0 + p1) + (p2 + p3);
            uintx2 dd;
            dd[0] = __builtin_amdgcn_perm(__float_as_uint(p1), __float_as_uint(p0), 0x07060302u);
            dd[1] = __builtin_amdgcn_perm(__float_as_uint(p3), __float_as_uint(p2), 0x07060302u);
            *(uintx2*)&pbuf[gb][j][prow * 44 + pk * 4] = dd;
        }

        // issue adj prefetch for group g+1 (stays in flight across barrier;
        // wraps harmlessly at g=15)
        {
            const int gn = (g + 1) & 15;
#pragma unroll
            for (int j = 0; j < 4; j++)
                adjr[j] = __builtin_nontemporal_load(
                    (const intx4*)(arp + ((gn * 4 + j + it0) & 63) * 32));
        }

        // one barrier per group: drain ds_writes only
        asm volatile("s_waitcnt lgkmcnt(0)" ::: "memory");
        __builtin_amdgcn_s_barrier();

        // CONSUME: 4 barrier-free iters; waves drift -> LDS/MFMA overlap
#pragma unroll
        for (int j = 0; j < 4; j++) {
            const int c = (g * 4 + j) & 1, n = c ^ 1;
            const int pxn = (g * 4 + j + 1 + it0) & 63;  // next flat tile
            breg[n][0] = *(const shortx8*)(bpp + (size_t)pxn * 16384);
            breg[n][1] = *(const shortx8*)(bpp + (size_t)pxn * 16384 + 512);

            __builtin_amdgcn_s_setprio(1);
#pragma unroll
            for (int rg = 0; rg < 8; rg++) {
                const shortx8 af = *(const shortx8*)&pbuf[gb][j][(rg * 16 + l15) * 44 + q * 8];
                acc[rg][0] = __builtin_amdgcn_mfma_f32_16x16x32_bf16(af, breg[c][0], acc[rg][0], 0, 0, 0);
                acc[rg][1] = __builtin_amdgcn_mfma_f32_16x16x32_bf16(af, breg[c][1], acc[rg][1], 0, 0, 0);
            }
            __builtin_amdgcn_s_setprio(0);
        }
    }

    // partial denominator: unique slot per thread, 128 threads total rows
    __syncthreads();
    lsp[pk][prow] = ls;
    __syncthreads();
    if (t < 128) {
        float s = 0.f;
#pragma unroll
        for (int kc = 0; kc < 8; kc++) s += lsp[kc][t];
        D[kq * NN + r0 + t] = s;
    }

    // partial output store: PLAIN stores -> P stays L3-resident for gat_fin
    float* Pq = P + (size_t)kq * ((size_t)NN * DOUT) + (size_t)r0 * DOUT;
#pragma unroll
    for (int rg = 0; rg < 8; rg++)
#pragma unroll
        for (int nt = 0; nt < 2; nt++) {
            const int col = w * 32 + nt * 16 + l15;
#pragma unroll
            for (int reg = 0; reg < 4; reg++) {
                const int row = rg * 16 + q * 4 + reg;
                Pq[(size_t)row * DOUT + col] = acc[rg][nt][reg];
            }
        }
}

// ---------------------------------------------------------------------------
// Kernel 3: finalize. out = ELU( (P0+P1+P2+P3) / (D0+D1+D2+D3) ), vectorized.
// 256 blocks x 1024 threads; block = 32 rows x 512 cols. P read with PLAIN
// loads (L3-resident); out written nontemporal (never re-read).
// ---------------------------------------------------------------------------
__global__ __launch_bounds__(1024) void gat_fin(
    const float* __restrict__ P, const float* __restrict__ D,
    float* __restrict__ out)
{
    const int t = threadIdx.x;
    const int r0 = blockIdx.x * 32;
    const int rr = t >> 7;           // 0..7
    const int c4 = (t & 127) * 4;    // col base
    const size_t Q = (size_t)NN * DOUT;
#pragma unroll
    for (int j = 0; j < 4; j++) {
        const int row = r0 + j * 8 + rr;
        const float den = ((D[row] + D[NN + row]) + (D[2 * NN + row] + D[3 * NN + row]));
        const float li = 1.f / den;
        const size_t off = (size_t)row * DOUT + c4;
        floatx4 v0 = *(const floatx4*)(P + off);
        floatx4 v1 = *(const floatx4*)(P + Q + off);
        floatx4 v2 = *(const floatx4*)(P + 2 * Q + off);
        floatx4 v3 = *(const floatx4*)(P + 3 * Q + off);
        floatx4 s;
#pragma unroll
        for (int i = 0; i < 4; i++) {
            float x = ((v0[i] + v1[i]) + (v2[i] + v3[i])) * li;
            s[i] = (x > 0.f) ? x : (__expf(x) - 1.f);
        }
        __builtin_nontemporal_store(s, (floatx4*)(out + off));
    }
}

// ---------------------------------------------------------------------------
extern "C" void kernel_launch(void* const* d_in, const int* in_sizes, int n_in,
                              void* d_out, int out_size, void* d_ws, size_t ws_size,
                              hipStream_t stream) {
    const float* h   = (const float*)d_in[0];
    const int*   adj = (const int*)d_in[1];
    const float* W   = (const float*)d_in[2];
    const float* a   = (const float*)d_in[3];
    float* out = (float*)d_out;

    char* ws = (char*)d_ws;
    unsigned short* WT    = (unsigned short*)ws;                  // 512 KB
    unsigned short* WhTt  = (unsigned short*)(ws + 524288);       // 8 MB (tiled)
    float*          f1    = (float*)(ws + 8912896);               // 32 KB
    float*          f2    = (float*)(ws + 8945664);               // 32 KB
    unsigned*       Menc  = (unsigned*)(ws + 8978432);            // 4 B
    float*          D     = (float*)(ws + 9437184);               // 128 KB (4x8192)
    float*          P     = (float*)(ws + 16777216);              // 64 MB (4x16MB)

    hipMemsetAsync(Menc, 0, 4, stream);
    transpose_w<<<256, 256, 0, stream>>>(W, WT);
    gemm_wh<<<256, 512, 0, stream>>>(h, WT, a, WhTt, f1, f2, Menc);
    gat_agg<<<256, 1024, 0, stream>>>(adj, WhTt, f1, f2, Menc, P, D);
    gat_fin<<<256, 1024, 0, stream>>>(P, D, out);
}

// Round 13
// 431.136 us; speedup vs baseline: 1.0251x; 1.0251x over previous
//
#include <hip/hip_runtime.h>
#include <stdint.h>

#define NN   8192
#define DIN  512
#define DOUT 512
#define ALPHA 0.2f

typedef float          floatx4  __attribute__((ext_vector_type(4)));
typedef float          floatx2  __attribute__((ext_vector_type(2)));
typedef short          shortx8  __attribute__((ext_vector_type(8)));
typedef unsigned short ushortx4 __attribute__((ext_vector_type(4)));
typedef int            intx2    __attribute__((ext_vector_type(2)));
typedef int            intx4    __attribute__((ext_vector_type(4)));
typedef unsigned       uintx2   __attribute__((ext_vector_type(2)));

__device__ inline unsigned short f2bf(float x) {
    union { float f; unsigned u; } v; v.f = x;
    return (unsigned short)((v.u + 0x7FFFu + ((v.u >> 16) & 1u)) >> 16);
}
__device__ inline unsigned encf(float x) {
    union { float f; unsigned u; } v; v.f = x;
    return (v.u & 0x80000000u) ? ~v.u : (v.u | 0x80000000u);
}
__device__ inline float decf(unsigned e) {
    union { float f; unsigned u; } v;
    v.u = (e & 0x80000000u) ? (e & 0x7FFFFFFFu) : ~e;
    return v.f;
}
__device__ inline float lrelu(float x) { return fmaxf(x, ALPHA * x); }

// ---------------------------------------------------------------------------
// Kernel T: WT[n][k] = bf16(W[k][n])   (512x512)
// ---------------------------------------------------------------------------
__global__ __launch_bounds__(256) void transpose_w(const float* __restrict__ W,
                                                   unsigned short* __restrict__ WT) {
    __shared__ float tile[32][33];
    const int t = threadIdx.x;
    const int x = t & 31, y = t >> 5;
    const int tr = (blockIdx.x >> 4) * 32, tc = (blockIdx.x & 15) * 32;
#pragma unroll
    for (int i = 0; i < 4; i++) {
        int r = y + i * 8;
        tile[r][x] = W[(size_t)(tr + r) * DOUT + tc + x];
    }
    __syncthreads();
#pragma unroll
    for (int i = 0; i < 4; i++) {
        int r = y + i * 8;
        WT[(size_t)(tc + r) * DIN + tr + x] = f2bf(tile[x][r]);
    }
}

// ---------------------------------------------------------------------------
// Kernel A: Wh = h @ W (bf16 MFMA). 512 blocks x 16 rows, 4 waves (16r x 128c).
// Writes Wh in k-major fragment-tiled layout WhTt[tile_k][tile_n][512],
// f1 = Wh@a1, f2 = Wh@a2, max(f2).  (R11 verbatim -- R16's 32-row variant
// regressed; reverted.)
// ---------------------------------------------------------------------------
__global__ __launch_bounds__(256) void gemm_wh(
    const float* __restrict__ h, const unsigned short* __restrict__ WT,
    const float* __restrict__ a, unsigned short* __restrict__ WhTt,
    float* __restrict__ f1, float* __restrict__ f2, unsigned* __restrict__ Menc)
{
    __shared__ float f1s[4][16], f2s[4][16];
    const int t = threadIdx.x;
    const int w = t >> 6, lane = t & 63, l15 = lane & 15, q = lane >> 4;
    const int r0 = blockIdx.x * 16;
    const int wc0 = w * 128;

    floatx4 acc[8];
    const floatx4 z4 = {0.f, 0.f, 0.f, 0.f};
#pragma unroll
    for (int j = 0; j < 8; j++) acc[j] = z4;

    const float* hp = &h[(size_t)(r0 + l15) * DIN + q * 8];
    const unsigned short* bp = &WT[(size_t)(wc0 + l15) * DIN + q * 8];

    floatx4 hA[2][2];
    shortx8 bB[2][8];
    hA[0][0] = *(const floatx4*)hp;
    hA[0][1] = *(const floatx4*)(hp + 4);
#pragma unroll
    for (int nt = 0; nt < 8; nt++)
        bB[0][nt] = *(const shortx8*)(bp + (size_t)nt * 16 * DIN);

#pragma unroll 2
    for (int it = 0; it < 16; ++it) {
        const int c = it & 1, n = c ^ 1;
        const int kn = ((it + 1) & 15) * 32;
        hA[n][0] = *(const floatx4*)(hp + kn);
        hA[n][1] = *(const floatx4*)(hp + kn + 4);
#pragma unroll
        for (int nt = 0; nt < 8; nt++)
            bB[n][nt] = *(const shortx8*)(bp + (size_t)nt * 16 * DIN + kn);

        shortx8 af;
#pragma unroll
        for (int j = 0; j < 8; j++)
            af[j] = (short)f2bf(hA[c][j >> 2][j & 3]);
#pragma unroll
        for (int nt = 0; nt < 8; nt++)
            acc[nt] = __builtin_amdgcn_mfma_f32_16x16x32_bf16(af, bB[c][nt], acc[nt], 0, 0, 0);
    }

    float a1v[8], a2v[8];
#pragma unroll
    for (int nt = 0; nt < 8; nt++) {
        int col = wc0 + nt * 16 + l15;
        a1v[nt] = a[col];
        a2v[nt] = a[DOUT + col];
    }
    {
        const int kk0 = r0 + q * 4;
        const int tile_k = kk0 >> 5;
        const int qq = (kk0 >> 3) & 3;
        const int j0 = kk0 & 7;
#pragma unroll
        for (int nt = 0; nt < 8; nt++) {
            const int tile_n = w * 8 + nt;
            ushortx4 pk;
#pragma unroll
            for (int reg = 0; reg < 4; reg++) pk[reg] = f2bf(acc[nt][reg]);
            *(ushortx4*)&WhTt[(((size_t)tile_k * 32 + tile_n) << 9) + qq * 128 + l15 * 8 + j0] = pk;
        }
    }
    float s1a[4], s2a[4];
#pragma unroll
    for (int reg = 0; reg < 4; reg++) {
        float s1 = 0.f, s2 = 0.f;
#pragma unroll
        for (int nt = 0; nt < 8; nt++) {
            s1 += acc[nt][reg] * a1v[nt];
            s2 += acc[nt][reg] * a2v[nt];
        }
        s1 += __shfl_xor(s1, 1, 64); s2 += __shfl_xor(s2, 1, 64);
        s1 += __shfl_xor(s1, 2, 64); s2 += __shfl_xor(s2, 2, 64);
        s1 += __shfl_xor(s1, 4, 64); s2 += __shfl_xor(s2, 4, 64);
        s1 += __shfl_xor(s1, 8, 64); s2 += __shfl_xor(s2, 8, 64);
        s1a[reg] = s1; s2a[reg] = s2;
    }
    if (l15 == 0) {
#pragma unroll
        for (int reg = 0; reg < 4; reg++) {
            f1s[w][q * 4 + reg] = s1a[reg];
            f2s[w][q * 4 + reg] = s2a[reg];
        }
    }
    __syncthreads();
    if (t < 16) {
        float v1 = f1s[0][t] + f1s[1][t] + f1s[2][t] + f1s[3][t];
        float v2 = f2s[0][t] + f2s[1][t] + f2s[2][t] + f2s[3][t];
        f1[r0 + t] = v1;
        f2[r0 + t] = v2;
        float mx = v2;
        mx = fmaxf(mx, __shfl_xor(mx, 1, 64));
        mx = fmaxf(mx, __shfl_xor(mx, 2, 64));
        mx = fmaxf(mx, __shfl_xor(mx, 4, 64));
        mx = fmaxf(mx, __shfl_xor(mx, 8, 64));
        if (t == 0) atomicMax(Menc, encf(mx));
    }
}

// ---------------------------------------------------------------------------
// Kernel 2: GAT aggregation. R17 = R11 VERBATIM (the 434.4 us champion).
// Every deviation tried since regressed: R12 64x64 tiles (+24), R13 spread
// produce (+66), R14 sandwiched produce + f2-global (+102), R15 tiled-P
// epilogue (+5), R16 pbuf stride 44 + 32-row gemm (+8). Structure: grid 256
// = rgid(64 x 128 rows) x kq(4 x 2048 k), kq = bid&3 XCD-constant; GRP=4
// grouped barrier (pbuf[2][4], produce 4 tiles clustered -> 1 lgkm-only
// barrier -> 4 barrier-free consume iters, waves drift so LDS/MFMA overlap
// across waves); f2s staged in LDS (lgkm pipe -- f2-from-global poisons the
// vmcnt FIFO and drains B prefetches, R13/R14); adj nontemporal prefetch one
// group ahead, in flight across barriers; group-aligned k-stagger spreads
// the XCD's 32 lockstep blocks over the L2-resident B quarter; setprio(1)
// around MFMA cluster; acc[8][2] (wave = 128r x 32c -- validated optimal vs
// c=64); plain row-major P stores (L3-resident for gat_fin).
// ---------------------------------------------------------------------------
__global__ __launch_bounds__(1024, 4) void gat_agg(
    const int* __restrict__ adj, const unsigned short* __restrict__ WhTt,
    const float* __restrict__ f1, const float* __restrict__ f2,
    const unsigned* __restrict__ Menc, float* __restrict__ P,
    float* __restrict__ D)
{
    __shared__ __align__(16) unsigned short pbuf[2][4][128 * 40]; // 80 KB
    __shared__ float f2s[2048];                                   // 8 KB
    __shared__ float lsp[8][128];                                 // 4 KB

    const int t = threadIdx.x;
    const int w = t >> 6, lane = t & 63, l15 = lane & 15, q = lane >> 4;
    const int prow = t >> 3, pk = t & 7;      // p ownership: row, 4-k chunk

    const int kq = blockIdx.x & 3;            // XCD-constant k-quarter
    const int rgid = blockIdx.x >> 2;
    const int r0 = rgid * 128;
    const int k0 = kq * 2048;
    const int it0 = ((blockIdx.x >> 3) * 4) & 63;  // group-aligned k-stagger

    // stage f2 slice for this k-quarter into LDS
    *(floatx2*)&f2s[t * 2] = *(const floatx2*)&f2[k0 + t * 2];

    const float M = decf(*Menc);
    const float f1v = f1[r0 + prow];
    const float mi = lrelu(f1v + M);

    floatx4 acc[8][2];
    const floatx4 z4 = {0.f, 0.f, 0.f, 0.f};
#pragma unroll
    for (int i = 0; i < 8; i++)
#pragma unroll
        for (int j = 0; j < 2; j++) acc[i][j] = z4;
    float ls = 0.f;

    // B base: tile_k = kq*64 + phys, tile_n = w*2 + nt (unique per wave)
    const unsigned short* bpp = WhTt
        + (((size_t)(kq * 64) * 32 + w * 2) << 9) + lane * 8;
    const int* arp = adj + (size_t)(r0 + prow) * NN + k0 + pk * 4;

    intx4   adjr[4];
    shortx8 breg[2][2];

    __syncthreads();   // f2s visible

    // prologue: adj for group 0 (phys tiles it0..it0+3); B for flat tile 0
#pragma unroll
    for (int j = 0; j < 4; j++)
        adjr[j] = __builtin_nontemporal_load((const intx4*)(arp + ((it0 + j) & 63) * 32));
    breg[0][0] = *(const shortx8*)(bpp + (size_t)it0 * 16384);
    breg[0][1] = *(const shortx8*)(bpp + (size_t)it0 * 16384 + 512);

#pragma unroll 1
    for (int g = 0; g < 16; ++g) {
        const int gb = g & 1;

        // PRODUCE: p for 4 tiles of group g -> pbuf[gb][0..3]
#pragma unroll
        for (int j = 0; j < 4; j++) {
            const int px = (g * 4 + j + it0) & 63;
            const floatx4 ff = *(const floatx4*)&f2s[px * 32 + pk * 4];
            const intx4   ad = adjr[j];
            float p0 = __expf(lrelu(f1v + ff[0]) - mi);
            float p1 = __expf(lrelu(f1v + ff[1]) - mi);
            float p2 = __expf(lrelu(f1v + ff[2]) - mi);
            float p3 = __expf(lrelu(f1v + ff[3]) - mi);
            p0 = (ad[0] > 0) ? p0 : 0.f;
            p1 = (ad[1] > 0) ? p1 : 0.f;
            p2 = (ad[2] > 0) ? p2 : 0.f;
            p3 = (ad[3] > 0) ? p3 : 0.f;
            ls += (p0 + p1) + (p2 + p3);
            uintx2 dd;
            dd[0] = __builtin_amdgcn_perm(__float_as_uint(p1), __float_as_uint(p0), 0x07060302u);
            dd[1] = __builtin_amdgcn_perm(__float_as_uint(p3), __float_as_uint(p2), 0x07060302u);
            *(uintx2*)&pbuf[gb][j][prow * 40 + pk * 4] = dd;
        }

        // issue adj prefetch for group g+1 (stays in flight across barrier;
        // wraps harmlessly at g=15)
        {
            const int gn = (g + 1) & 15;
#pragma unroll
            for (int j = 0; j < 4; j++)
                adjr[j] = __builtin_nontemporal_load(
                    (const intx4*)(arp + ((gn * 4 + j + it0) & 63) * 32));
        }

        // one barrier per group: drain ds_writes only
        asm volatile("s_waitcnt lgkmcnt(0)" ::: "memory");
        __builtin_amdgcn_s_barrier();

        // CONSUME: 4 barrier-free iters; waves drift -> LDS/MFMA overlap
#pragma unroll
        for (int j = 0; j < 4; j++) {
            const int c = (g * 4 + j) & 1, n = c ^ 1;
            const int pxn = (g * 4 + j + 1 + it0) & 63;  // next flat tile
            breg[n][0] = *(const shortx8*)(bpp + (size_t)pxn * 16384);
            breg[n][1] = *(const shortx8*)(bpp + (size_t)pxn * 16384 + 512);

            __builtin_amdgcn_s_setprio(1);
#pragma unroll
            for (int rg = 0; rg < 8; rg++) {
                const shortx8 af = *(const shortx8*)&pbuf[gb][j][(rg * 16 + l15) * 40 + q * 8];
                acc[rg][0] = __builtin_amdgcn_mfma_f32_16x16x32_bf16(af, breg[c][0], acc[rg][0], 0, 0, 0);
                acc[rg][1] = __builtin_amdgcn_mfma_f32_16x16x32_bf16(af, breg[c][1], acc[rg][1], 0, 0, 0);
            }
            __builtin_amdgcn_s_setprio(0);
        }
    }

    // partial denominator: unique slot per thread, 128 threads total rows
    __syncthreads();
    lsp[pk][prow] = ls;
    __syncthreads();
    if (t < 128) {
        float s = 0.f;
#pragma unroll
        for (int kc = 0; kc < 8; kc++) s += lsp[kc][t];
        D[kq * NN + r0 + t] = s;
    }

    // partial output store: PLAIN stores -> P stays L3-resident for gat_fin
    float* Pq = P + (size_t)kq * ((size_t)NN * DOUT) + (size_t)r0 * DOUT;
#pragma unroll
    for (int rg = 0; rg < 8; rg++)
#pragma unroll
        for (int nt = 0; nt < 2; nt++) {
            const int col = w * 32 + nt * 16 + l15;
#pragma unroll
            for (int reg = 0; reg < 4; reg++) {
                const int row = rg * 16 + q * 4 + reg;
                Pq[(size_t)row * DOUT + col] = acc[rg][nt][reg];
            }
        }
}

// ---------------------------------------------------------------------------
// Kernel 3: finalize. out = ELU( (P0+P1+P2+P3) / (D0+D1+D2+D3) ), vectorized.
// 256 blocks x 1024 threads; block = 32 rows x 512 cols. P read with PLAIN
// loads (L3-resident); out written nontemporal (never re-read).
// ---------------------------------------------------------------------------
__global__ __launch_bounds__(1024) void gat_fin(
    const float* __restrict__ P, const float* __restrict__ D,
    float* __restrict__ out)
{
    const int t = threadIdx.x;
    const int r0 = blockIdx.x * 32;
    const int rr = t >> 7;           // 0..7
    const int c4 = (t & 127) * 4;    // col base
    const size_t Q = (size_t)NN * DOUT;
#pragma unroll
    for (int j = 0; j < 4; j++) {
        const int row = r0 + j * 8 + rr;
        const float den = ((D[row] + D[NN + row]) + (D[2 * NN + row] + D[3 * NN + row]));
        const float li = 1.f / den;
        const size_t off = (size_t)row * DOUT + c4;
        floatx4 v0 = *(const floatx4*)(P + off);
        floatx4 v1 = *(const floatx4*)(P + Q + off);
        floatx4 v2 = *(const floatx4*)(P + 2 * Q + off);
        floatx4 v3 = *(const floatx4*)(P + 3 * Q + off);
        floatx4 s;
#pragma unroll
        for (int i = 0; i < 4; i++) {
            float x = ((v0[i] + v1[i]) + (v2[i] + v3[i])) * li;
            s[i] = (x > 0.f) ? x : (__expf(x) - 1.f);
        }
        __builtin_nontemporal_store(s, (floatx4*)(out + off));
    }
}

// ---------------------------------------------------------------------------
extern "C" void kernel_launch(void* const* d_in, const int* in_sizes, int n_in,
                              void* d_out, int out_size, void* d_ws, size_t ws_size,
                              hipStream_t stream) {
    const float* h   = (const float*)d_in[0];
    const int*   adj = (const int*)d_in[1];
    const float* W   = (const float*)d_in[2];
    const float* a   = (const float*)d_in[3];
    float* out = (float*)d_out;

    char* ws = (char*)d_ws;
    unsigned short* WT    = (unsigned short*)ws;                  // 512 KB
    unsigned short* WhTt  = (unsigned short*)(ws + 524288);       // 8 MB (tiled)
    float*          f1    = (float*)(ws + 8912896);               // 32 KB
    float*          f2    = (float*)(ws + 8945664);               // 32 KB
    unsigned*       Menc  = (unsigned*)(ws + 8978432);            // 4 B
    float*          D     = (float*)(ws + 9437184);               // 128 KB (4x8192)
    float*          P     = (float*)(ws + 16777216);              // 64 MB (4x16MB)

    hipMemsetAsync(Menc, 0, 4, stream);
    transpose_w<<<256, 256, 0, stream>>>(W, WT);
    gemm_wh<<<512, 256, 0, stream>>>(h, WT, a, WhTt, f1, f2, Menc);
    gat_agg<<<256, 1024, 0, stream>>>(adj, WhTt, f1, f2, Menc, P, D);
    gat_fin<<<256, 1024, 0, stream>>>(P, D, out);
}